// Round 4
// baseline (360.089 us; speedup 1.0000x reference)
//
#include <hip/hip_runtime.h>
#include <math.h>

#define NROWS 65536
#define ED 64
#define NE 2048
#define TAU 1e-3f

typedef _Float16 f16x8 __attribute__((ext_vector_type(8)));
typedef float f32x4 __attribute__((ext_vector_type(4)));

// workspace layout (float offsets)
#define WS_CBH      0        // fp16[2048*64] = 65536 float slots
#define WS_MROW     131072   // float[65536]
#define WS_PPART    196608   // float[256*2048]
#define WS_FLAGCNT  720896   // int[1] (+pad)
#define WS_FLAGLIST 720912   // int[65536]
#define WS_COUNTS   786448   // float[2048]
#define WS_PSUM     788496   // float[2048]
#define WS_MPART    790544   // float[64]

// output layout (float offsets): z_q_st, commit, kl, lb, cb, perplexity
#define OUT_ZQ     0
#define OUT_COMMIT 4194304
#define OUT_KL     4194305
#define OUT_LB     4194306
#define OUT_CB     4194307
#define OUT_PERP   4325379

__global__ void k_cb(const float* __restrict__ emb, _Float16* __restrict__ cbh,
                     float* __restrict__ cbo) {
    int t = blockIdx.x * blockDim.x + threadIdx.x;
    int row = t >> 6;
    int lane = t & 63;
    if (row >= NE) return;
    float v = emb[row * ED + lane];
    float sq = v * v;
#pragma unroll
    for (int off = 32; off > 0; off >>= 1) sq += __shfl_xor(sq, off);
    float c = v * (1.0f / fmaxf(sqrtf(sq), 1e-12f));
    cbo[row * ED + lane] = c;
    cbh[row * ED + lane] = (_Float16)c;
}

// Transposed fused GEMM: cb = A operand, z = B operand.
// C layout: col(lane&15) = z-row, row(lane>>4)*4+i = codeword.
// 256 blocks x 1024 threads (16 waves); wave w owns codewords [w*128, w*128+128).
// Block processes 16 tiles of 16 z-rows. z_q gather + counts fused.
__launch_bounds__(1024, 4)
__global__ void k_main(const float* __restrict__ z, const _Float16* __restrict__ cbh,
                       const float* __restrict__ cb32, float* __restrict__ zq,
                       float* __restrict__ mrow, float* __restrict__ ppart,
                       int* __restrict__ flagcnt, int* __restrict__ flaglist,
                       float* __restrict__ counts) {
    __shared__ float st_m[16][16], st_m2[16][16], st_s[16][16];
    __shared__ int   st_i[16][16];
    __shared__ int   idxs[16];

    const int tid = threadIdx.x;
    const int lane = tid & 63;
    const int w = tid >> 6;               // 0..15
    const int l15 = lane & 15;            // z-row within tile
    const int lg = lane >> 4;             // 0..3
    const int cwbase = w * 128;

    f32x4 pcol[8];
#pragma unroll
    for (int jf = 0; jf < 8; ++jf) pcol[jf] = (f32x4){0.f, 0.f, 0.f, 0.f};

    const _Float16* cwp = cbh + (size_t)(cwbase + l15) * ED + lg * 8;

    for (int t = 0; t < 16; ++t) {
        const int rowbase = (blockIdx.x * 16 + t) * 16;
        // ---- A: load z slice, normalize, build fp16 B fragments ----
        const float4* zp4 = (const float4*)(z + (size_t)(rowbase + l15) * ED + lg * 8);
        const float4 za0 = zp4[0], za1 = zp4[1];     // k = lg*8 .. +7
        const float4 zb0 = zp4[8], zb1 = zp4[9];     // k = 32+lg*8 .. +7
        float sq = za0.x*za0.x + za0.y*za0.y + za0.z*za0.z + za0.w*za0.w
                 + za1.x*za1.x + za1.y*za1.y + za1.z*za1.z + za1.w*za1.w
                 + zb0.x*zb0.x + zb0.y*zb0.y + zb0.z*zb0.z + zb0.w*zb0.w
                 + zb1.x*zb1.x + zb1.y*zb1.y + zb1.z*zb1.z + zb1.w*zb1.w;
        sq += __shfl_xor(sq, 16);
        sq += __shfl_xor(sq, 32);
        const float invn = 1.0f / fmaxf(sqrtf(sq), 1e-12f);
        f16x8 bh0, bh1;
        bh0[0]=(_Float16)(za0.x*invn); bh0[1]=(_Float16)(za0.y*invn);
        bh0[2]=(_Float16)(za0.z*invn); bh0[3]=(_Float16)(za0.w*invn);
        bh0[4]=(_Float16)(za1.x*invn); bh0[5]=(_Float16)(za1.y*invn);
        bh0[6]=(_Float16)(za1.z*invn); bh0[7]=(_Float16)(za1.w*invn);
        bh1[0]=(_Float16)(zb0.x*invn); bh1[1]=(_Float16)(zb0.y*invn);
        bh1[2]=(_Float16)(zb0.z*invn); bh1[3]=(_Float16)(zb0.w*invn);
        bh1[4]=(_Float16)(zb1.x*invn); bh1[5]=(_Float16)(zb1.y*invn);
        bh1[6]=(_Float16)(zb1.z*invn); bh1[7]=(_Float16)(zb1.w*invn);

        // ---- 8 codeword tiles: mfma + branchless stats + exp ----
        f32x4 acc[8];
        float m = -2.f, m2 = -2.f, s = 0.f;
        int mi = 0;
#pragma unroll
        for (int jf = 0; jf < 8; ++jf) {
            const _Float16* ap = cwp + (size_t)jf * 16 * ED;
            const f16x8 a0 = *(const f16x8*)(ap);
            const f16x8 a1 = *(const f16x8*)(ap + 32);
            f32x4 c = (f32x4){0.f, 0.f, 0.f, 0.f};
            c = __builtin_amdgcn_mfma_f32_16x16x32_f16(a0, bh0, c, 0, 0, 0);
            c = __builtin_amdgcn_mfma_f32_16x16x32_f16(a1, bh1, c, 0, 0, 0);
            const int cw0 = cwbase + jf * 16 + lg * 4;
#pragma unroll
            for (int i = 0; i < 4; ++i) {
                const float v = c[i];
                m2 = fmaxf(m2, fminf(v, m));
                mi = (v > m) ? (cw0 + i) : mi;
                m  = fmaxf(v, m);
                const float e = __expf(v);
                s += e;
                c[i] = e;
            }
            acc[jf] = c;
        }
        // reduce stats over the 4 lg lanes sharing this z-row
#pragma unroll
        for (int d = 16; d <= 32; d <<= 1) {
            const float om  = __shfl_xor(m, d);
            const float om2 = __shfl_xor(m2, d);
            const int   oi  = __shfl_xor(mi, d);
            const float os  = __shfl_xor(s, d);
            s += os;
            const float nm2 = fmaxf(fmaxf(m2, om2), fminf(m, om));
            const bool take = (om > m) || (om == m && oi < mi);
            mi = take ? oi : mi;
            m  = take ? om : m;
            m2 = nm2;
        }
        if (lane < 16) {
            st_m[w][lane] = m; st_m2[w][lane] = m2; st_s[w][lane] = s; st_i[w][lane] = mi;
        }
        __syncthreads();
        // ---- B: all-lane redundant denominator combine ----
        float ss = 0.f;
#pragma unroll
        for (int u = 0; u < 16; ++u) ss += st_s[u][l15];
        if (w == 0 && lane < 16) {        // argmax/m combine, side outputs
            float mm = st_m[0][lane], mm2 = st_m2[0][lane];
            int ii = st_i[0][lane];
#pragma unroll
            for (int u = 1; u < 16; ++u) {
                const float om = st_m[u][lane], om2 = st_m2[u][lane];
                const int oi = st_i[u][lane];
                const float nm2 = fmaxf(fmaxf(mm2, om2), fminf(mm, om));
                const bool take = (om > mm) || (om == mm && oi < ii);
                ii = take ? oi : ii;
                mm = take ? om : mm;
                mm2 = nm2;
            }
            const int grow = rowbase + lane;
            mrow[grow] = mm;
            idxs[lane] = ii;
            if (mm - mm2 < TAU) {         // ambiguous -> exact recheck patches later
                int e = atomicAdd(flagcnt, 1);
                flaglist[e] = grow;
            } else {
                atomicAdd(&counts[ii], 1.0f);
            }
        }
        // ---- C: p accumulation (registers only) ----
        const float r = 1.0f / ss;
#pragma unroll
        for (int jf = 0; jf < 8; ++jf) {
#pragma unroll
            for (int i = 0; i < 4; ++i)
                pcol[jf][i] = fmaf(acc[jf][i], r, pcol[jf][i]);
        }
        __syncthreads();
        // ---- D: z_q gather for this tile (wave w -> row w) ----
        zq[(size_t)(rowbase + w) * ED + lane] = cb32[(size_t)idxs[w] * ED + lane];
    }
    // ---- epilogue: reduce pcol over the 16 l15 lanes, store block partial ----
#pragma unroll
    for (int jf = 0; jf < 8; ++jf) {
#pragma unroll
        for (int i = 0; i < 4; ++i) {
            float v = pcol[jf][i];
            v += __shfl_xor(v, 1);
            v += __shfl_xor(v, 2);
            v += __shfl_xor(v, 4);
            v += __shfl_xor(v, 8);
            pcol[jf][i] = v;
        }
    }
    if (l15 == 0) {
        float* pp = ppart + (size_t)blockIdx.x * NE + cwbase;
#pragma unroll
        for (int jf = 0; jf < 8; ++jf) {
            float4 st;
            st.x = pcol[jf][0]; st.y = pcol[jf][1]; st.z = pcol[jf][2]; st.w = pcol[jf][3];
            *(float4*)(pp + jf * 16 + lg * 4) = st;
        }
    }
}

// Exact fp32 re-scan for flagged rows, 4 rows per codebook pass.
// Patches mrow, counts, and the z_q row.
__launch_bounds__(256)
__global__ void k_recheck(const float* __restrict__ z, const float* __restrict__ cb32,
                          const int* __restrict__ flagcnt, const int* __restrict__ flaglist,
                          float* __restrict__ mrow, float* __restrict__ counts,
                          float* __restrict__ zq) {
    __shared__ float zn[4][ED];
    __shared__ float rbv[4][4];
    __shared__ int   rbi[4][4];
    __shared__ int   rrow[4];
    __shared__ int   bsel[4];
    const int n = *flagcnt;
    const int tid = threadIdx.x, lane = tid & 63, wv = tid >> 6;
    for (int base = blockIdx.x * 4; base < n; base += gridDim.x * 4) {
        __syncthreads();
        {
            const int e = base + wv;
            int row = 0;
            if (e < n) row = flaglist[e];
            if (lane == 0) rrow[wv] = (e < n) ? row : -1;
            float v = (e < n) ? z[(size_t)row * ED + lane] : 0.f;
            float sq = v * v;
#pragma unroll
            for (int d = 32; d > 0; d >>= 1) sq += __shfl_xor(sq, d);
            zn[wv][lane] = v * (1.0f / fmaxf(sqrtf(sq), 1e-12f));
        }
        __syncthreads();
        float b0 = -2.f, b1 = -2.f, b2 = -2.f, b3 = -2.f;
        int i0 = 0, i1 = 0, i2 = 0, i3 = 0;
        for (int q = 0; q < 8; ++q) {
            const int j = q * 256 + tid;
            const float* cj = cb32 + (size_t)j * ED;
            float a0 = 0.f, a1 = 0.f, a2 = 0.f, a3 = 0.f;
#pragma unroll
            for (int k = 0; k < ED; k += 4) {
                const float4 c4 = *(const float4*)(cj + k);
                a0 = fmaf(zn[0][k], c4.x, a0); a0 = fmaf(zn[0][k+1], c4.y, a0);
                a0 = fmaf(zn[0][k+2], c4.z, a0); a0 = fmaf(zn[0][k+3], c4.w, a0);
                a1 = fmaf(zn[1][k], c4.x, a1); a1 = fmaf(zn[1][k+1], c4.y, a1);
                a1 = fmaf(zn[1][k+2], c4.z, a1); a1 = fmaf(zn[1][k+3], c4.w, a1);
                a2 = fmaf(zn[2][k], c4.x, a2); a2 = fmaf(zn[2][k+1], c4.y, a2);
                a2 = fmaf(zn[2][k+2], c4.z, a2); a2 = fmaf(zn[2][k+3], c4.w, a2);
                a3 = fmaf(zn[3][k], c4.x, a3); a3 = fmaf(zn[3][k+1], c4.y, a3);
                a3 = fmaf(zn[3][k+2], c4.z, a3); a3 = fmaf(zn[3][k+3], c4.w, a3);
            }
            i0 = (a0 > b0) ? j : i0; b0 = fmaxf(a0, b0);
            i1 = (a1 > b1) ? j : i1; b1 = fmaxf(a1, b1);
            i2 = (a2 > b2) ? j : i2; b2 = fmaxf(a2, b2);
            i3 = (a3 > b3) ? j : i3; b3 = fmaxf(a3, b3);
        }
#pragma unroll
        for (int d = 1; d < 64; d <<= 1) {
            float o; int oi; bool tk;
            o = __shfl_xor(b0, d); oi = __shfl_xor(i0, d);
            tk = (o > b0) || (o == b0 && oi < i0); b0 = tk ? o : b0; i0 = tk ? oi : i0;
            o = __shfl_xor(b1, d); oi = __shfl_xor(i1, d);
            tk = (o > b1) || (o == b1 && oi < i1); b1 = tk ? o : b1; i1 = tk ? oi : i1;
            o = __shfl_xor(b2, d); oi = __shfl_xor(i2, d);
            tk = (o > b2) || (o == b2 && oi < i2); b2 = tk ? o : b2; i2 = tk ? oi : i2;
            o = __shfl_xor(b3, d); oi = __shfl_xor(i3, d);
            tk = (o > b3) || (o == b3 && oi < i3); b3 = tk ? o : b3; i3 = tk ? oi : i3;
        }
        if (lane == 0) {
            rbv[wv][0] = b0; rbi[wv][0] = i0; rbv[wv][1] = b1; rbi[wv][1] = i1;
            rbv[wv][2] = b2; rbi[wv][2] = i2; rbv[wv][3] = b3; rbi[wv][3] = i3;
        }
        __syncthreads();
        if (tid < 4) {
            const int e = base + tid;
            if (e < n) {
                float bv = rbv[0][tid]; int bi_ = rbi[0][tid];
#pragma unroll
                for (int u = 1; u < 4; ++u) {
                    const float o = rbv[u][tid]; const int oi = rbi[u][tid];
                    const bool tk = (o > bv) || (o == bv && oi < bi_);
                    bv = tk ? o : bv; bi_ = tk ? oi : bi_;
                }
                const int row = rrow[tid];
                mrow[row] = bv;
                bsel[tid] = bi_;
                atomicAdd(&counts[bi_], 1.0f);
            }
        }
        __syncthreads();
        {   // rewrite z_q rows with exact selection
            const int r = tid >> 6;       // 0..3
            if (base + r < n) {
                const int row = rrow[r];
                zq[(size_t)row * ED + lane] = cb32[(size_t)bsel[r] * ED + lane];
            }
        }
    }
}

// Parallel reductions: blocks 0..7 sum ppart columns; blocks 8..71 sum mrow.
__global__ void k_red(const float* __restrict__ ppart, const float* __restrict__ mrow,
                      float* __restrict__ psum, float* __restrict__ mpart) {
    const int tid = threadIdx.x;
    if (blockIdx.x < 8) {
        const int col = blockIdx.x * 256 + tid;
        float s = 0.f;
        for (int sl = 0; sl < 256; ++sl) s += ppart[(size_t)sl * NE + col];
        psum[col] = s;
    } else {
        __shared__ float lds[4];
        const int b = blockIdx.x - 8;     // 0..63
        const int r0 = b * 1024;
        float s = 0.f;
        for (int r = r0 + tid; r < r0 + 1024; r += 256) s += mrow[r];
        const int lane = tid & 63, wv = tid >> 6;
#pragma unroll
        for (int d = 32; d > 0; d >>= 1) s += __shfl_xor(s, d);
        if (lane == 0) lds[wv] = s;
        __syncthreads();
        if (tid == 0) mpart[b] = lds[0] + lds[1] + lds[2] + lds[3];
    }
}

__device__ __forceinline__ float block_reduce_1024(float v, float* lds, int lane, int wid) {
#pragma unroll
    for (int off = 32; off > 0; off >>= 1) v += __shfl_xor(v, off);
    if (lane == 0) lds[wid] = v;
    __syncthreads();
    float r = 0.f;
    if (wid == 0) {
        r = (lane < 16) ? lds[lane] : 0.f;
#pragma unroll
        for (int off = 8; off > 0; off >>= 1) r += __shfl_xor(r, off);
    }
    __syncthreads();
    return r;
}

__global__ void k_final(const float* __restrict__ counts, const float* __restrict__ psum,
                        const float* __restrict__ mpart, float* __restrict__ out) {
    __shared__ float lds[16];
    const int tid = threadIdx.x;          // 1024
    const int lane = tid & 63, wid = tid >> 6;
    float sm = (tid < 64) ? mpart[tid] : 0.f;
    float kl = 0.f, lb = 0.f, H = 0.f;
    const float LOGNE = logf((float)NE);
    for (int j = tid; j < NE; j += 1024) {
        const float p = psum[j] * (1.0f / NROWS);
        const float em = counts[j] * (1.0f / NROWS);
        kl += p * (logf(p) + LOGNE);
        lb += em * p;
        H += em * logf(em + 1e-6f);
    }
    sm = block_reduce_1024(sm, lds, lane, wid);
    kl = block_reduce_1024(kl, lds, lane, wid);
    lb = block_reduce_1024(lb, lds, lane, wid);
    H  = block_reduce_1024(H,  lds, lane, wid);
    if (tid == 0) {
        out[OUT_COMMIT] = 1.25f * (1.0f - sm * (1.0f / NROWS));
        out[OUT_KL] = kl;
        out[OUT_LB] = lb;
        out[OUT_PERP] = expf(-H);
    }
}

extern "C" void kernel_launch(void* const* d_in, const int* in_sizes, int n_in,
                              void* d_out, int out_size, void* d_ws, size_t ws_size,
                              hipStream_t stream) {
    const float* z   = (const float*)d_in[0];
    const float* emb = (const float*)d_in[1];
    float* out = (float*)d_out;
    float* ws  = (float*)d_ws;

    _Float16* cbh  = (_Float16*)(ws + WS_CBH);
    float* mrowp   = ws + WS_MROW;
    float* ppart   = ws + WS_PPART;
    int* flagcnt   = (int*)(ws + WS_FLAGCNT);
    int* flaglist  = (int*)(ws + WS_FLAGLIST);
    float* counts  = ws + WS_COUNTS;
    float* psum    = ws + WS_PSUM;
    float* mpart   = ws + WS_MPART;
    float* cb32    = out + OUT_CB;

    hipMemsetAsync(flagcnt, 0, sizeof(int), stream);
    hipMemsetAsync(counts, 0, NE * sizeof(float), stream);

    k_cb      <<<512, 256, 0, stream>>>(emb, cbh, cb32);
    k_main    <<<256, 1024, 0, stream>>>(z, cbh, cb32, out + OUT_ZQ, mrowp, ppart,
                                         flagcnt, flaglist, counts);
    k_recheck <<<512, 256, 0, stream>>>(z, cb32, flagcnt, flaglist, mrowp, counts,
                                        out + OUT_ZQ);
    k_red     <<<72, 256, 0, stream>>>(ppart, mrowp, psum, mpart);
    k_final   <<<1, 1024, 0, stream>>>(counts, psum, mpart, out);
}

// Round 5
// 357.794 us; speedup vs baseline: 1.0064x; 1.0064x over previous
//
#include <hip/hip_runtime.h>
#include <math.h>

#define NROWS 65536
#define ED 64
#define NE 2048
#define TAU 1e-3f

typedef _Float16 f16x8 __attribute__((ext_vector_type(8)));
typedef float f32x4 __attribute__((ext_vector_type(4)));

// workspace layout (float offsets) — ppart LAST so its slice count can adapt
#define WS_CBH      0        // fp16[2048*64] = 65536 float slots
#define WS_MROW     65536    // float[65536]
#define WS_FLAGCNT  131072   // int[1] (+pad)
#define WS_FLAGLIST 131088   // int[65536]
#define WS_COUNTS   196624   // float[2048]
#define WS_PSUM     198672   // float[2048]
#define WS_MPART    200720   // float[64] (+pad)
#define WS_PPART    200832   // float[nblk*2048]

// output layout (float offsets): z_q_st, commit, kl, lb, cb, perplexity
#define OUT_ZQ     0
#define OUT_COMMIT 4194304
#define OUT_KL     4194305
#define OUT_LB     4194306
#define OUT_CB     4194307
#define OUT_PERP   4325379

__global__ void k_cb(const float* __restrict__ emb, _Float16* __restrict__ cbh,
                     float* __restrict__ cbo) {
    int t = blockIdx.x * blockDim.x + threadIdx.x;
    int row = t >> 6;
    int lane = t & 63;
    if (row >= NE) return;
    float v = emb[row * ED + lane];
    float sq = v * v;
#pragma unroll
    for (int off = 32; off > 0; off >>= 1) sq += __shfl_xor(sq, off);
    float c = v * (1.0f / fmaxf(sqrtf(sq), 1e-12f));
    cbo[row * ED + lane] = c;
    cbh[row * ED + lane] = (_Float16)c;
}

// Transposed fused GEMM: cb = A operand, z = B operand.
// C layout: col(lane&15) = z-row, row(lane>>4)*4+i = codeword.
// nblk blocks x 512 threads (8 waves); wave w owns codewords [w*256, w*256+256).
// Block processes tpb tiles of 16 z-rows. z_q gather + counts fused.
__launch_bounds__(512, 2)
__global__ void k_main(const float* __restrict__ z, const _Float16* __restrict__ cbh,
                       const float* __restrict__ cb32, float* __restrict__ zq,
                       float* __restrict__ mrow, float* __restrict__ ppart,
                       int* __restrict__ flagcnt, int* __restrict__ flaglist,
                       float* __restrict__ counts, int tpb) {
    __shared__ float st_m[8][16], st_m2[8][16], st_s[8][16];
    __shared__ int   st_i[8][16];
    __shared__ int   idxs[16];

    const int tid = threadIdx.x;
    const int lane = tid & 63;
    const int w = tid >> 6;               // 0..7
    const int l15 = lane & 15;            // z-row within tile
    const int lg = lane >> 4;             // 0..3
    const int cwbase = w * 256;

    f32x4 pcol[16];
#pragma unroll
    for (int jf = 0; jf < 16; ++jf) pcol[jf] = (f32x4){0.f, 0.f, 0.f, 0.f};

    const _Float16* cwp = cbh + (size_t)(cwbase + l15) * ED + lg * 8;

    for (int t = 0; t < tpb; ++t) {
        const int rowbase = (blockIdx.x * tpb + t) * 16;
        // ---- A: load z slice, normalize, build fp16 B fragments ----
        const float4* zp4 = (const float4*)(z + (size_t)(rowbase + l15) * ED + lg * 8);
        const float4 za0 = zp4[0], za1 = zp4[1];     // k = lg*8 .. +7
        const float4 zb0 = zp4[8], zb1 = zp4[9];     // k = 32+lg*8 .. +7
        float sq = za0.x*za0.x + za0.y*za0.y + za0.z*za0.z + za0.w*za0.w
                 + za1.x*za1.x + za1.y*za1.y + za1.z*za1.z + za1.w*za1.w
                 + zb0.x*zb0.x + zb0.y*zb0.y + zb0.z*zb0.z + zb0.w*zb0.w
                 + zb1.x*zb1.x + zb1.y*zb1.y + zb1.z*zb1.z + zb1.w*zb1.w;
        sq += __shfl_xor(sq, 16);
        sq += __shfl_xor(sq, 32);
        const float invn = 1.0f / fmaxf(sqrtf(sq), 1e-12f);
        f16x8 bh0, bh1;
        bh0[0]=(_Float16)(za0.x*invn); bh0[1]=(_Float16)(za0.y*invn);
        bh0[2]=(_Float16)(za0.z*invn); bh0[3]=(_Float16)(za0.w*invn);
        bh0[4]=(_Float16)(za1.x*invn); bh0[5]=(_Float16)(za1.y*invn);
        bh0[6]=(_Float16)(za1.z*invn); bh0[7]=(_Float16)(za1.w*invn);
        bh1[0]=(_Float16)(zb0.x*invn); bh1[1]=(_Float16)(zb0.y*invn);
        bh1[2]=(_Float16)(zb0.z*invn); bh1[3]=(_Float16)(zb0.w*invn);
        bh1[4]=(_Float16)(zb1.x*invn); bh1[5]=(_Float16)(zb1.y*invn);
        bh1[6]=(_Float16)(zb1.z*invn); bh1[7]=(_Float16)(zb1.w*invn);

        // ---- 16 codeword tiles: mfma + branchless stats + exp ----
        f32x4 acc[16];
        float m = -2.f, m2 = -2.f, s = 0.f;
        int mi = 0;
#pragma unroll
        for (int jf = 0; jf < 16; ++jf) {
            const _Float16* ap = cwp + (size_t)jf * 16 * ED;
            const f16x8 a0 = *(const f16x8*)(ap);
            const f16x8 a1 = *(const f16x8*)(ap + 32);
            f32x4 c = (f32x4){0.f, 0.f, 0.f, 0.f};
            c = __builtin_amdgcn_mfma_f32_16x16x32_f16(a0, bh0, c, 0, 0, 0);
            c = __builtin_amdgcn_mfma_f32_16x16x32_f16(a1, bh1, c, 0, 0, 0);
            const int cw0 = cwbase + jf * 16 + lg * 4;
#pragma unroll
            for (int i = 0; i < 4; ++i) {
                const float v = c[i];
                m2 = fmaxf(m2, fminf(v, m));
                mi = (v > m) ? (cw0 + i) : mi;
                m  = fmaxf(v, m);
                const float e = __expf(v);
                s += e;
                c[i] = e;
            }
            acc[jf] = c;
        }
        // reduce stats over the 4 lg lanes sharing this z-row
#pragma unroll
        for (int d = 16; d <= 32; d <<= 1) {
            const float om  = __shfl_xor(m, d);
            const float om2 = __shfl_xor(m2, d);
            const int   oi  = __shfl_xor(mi, d);
            const float os  = __shfl_xor(s, d);
            s += os;
            const float nm2 = fmaxf(fmaxf(m2, om2), fminf(m, om));
            const bool take = (om > m) || (om == m && oi < mi);
            mi = take ? oi : mi;
            m  = take ? om : m;
            m2 = nm2;
        }
        if (lane < 16) {
            st_m[w][lane] = m; st_m2[w][lane] = m2; st_s[w][lane] = s; st_i[w][lane] = mi;
        }
        __syncthreads();
        // ---- B: all-lane redundant denominator combine ----
        float ss = 0.f;
#pragma unroll
        for (int u = 0; u < 8; ++u) ss += st_s[u][l15];
        if (w == 0 && lane < 16) {        // argmax/m combine, side outputs
            float mm = st_m[0][lane], mm2 = st_m2[0][lane];
            int ii = st_i[0][lane];
#pragma unroll
            for (int u = 1; u < 8; ++u) {
                const float om = st_m[u][lane], om2 = st_m2[u][lane];
                const int oi = st_i[u][lane];
                const float nm2 = fmaxf(fmaxf(mm2, om2), fminf(mm, om));
                const bool take = (om > mm) || (om == mm && oi < ii);
                ii = take ? oi : ii;
                mm = take ? om : mm;
                mm2 = nm2;
            }
            const int grow = rowbase + lane;
            mrow[grow] = mm;
            idxs[lane] = ii;
            if (mm - mm2 < TAU) {         // ambiguous -> exact recheck patches later
                int e = atomicAdd(flagcnt, 1);
                flaglist[e] = grow;
            } else {
                atomicAdd(&counts[ii], 1.0f);
            }
        }
        // ---- C: p accumulation (registers only) ----
        const float r = 1.0f / ss;
#pragma unroll
        for (int jf = 0; jf < 16; ++jf) {
#pragma unroll
            for (int i = 0; i < 4; ++i)
                pcol[jf][i] = fmaf(acc[jf][i], r, pcol[jf][i]);
        }
        __syncthreads();
        // ---- D: z_q gather for this tile (wave w -> rows w, w+8) ----
#pragma unroll
        for (int rr = 0; rr < 2; ++rr) {
            const int r16 = w + rr * 8;
            zq[(size_t)(rowbase + r16) * ED + lane] = cb32[(size_t)idxs[r16] * ED + lane];
        }
    }
    // ---- epilogue: reduce pcol over the 16 l15 lanes, store block partial ----
#pragma unroll
    for (int jf = 0; jf < 16; ++jf) {
#pragma unroll
        for (int i = 0; i < 4; ++i) {
            float v = pcol[jf][i];
            v += __shfl_xor(v, 1);
            v += __shfl_xor(v, 2);
            v += __shfl_xor(v, 4);
            v += __shfl_xor(v, 8);
            pcol[jf][i] = v;
        }
    }
    if (l15 == 0) {
        float* pp = ppart + (size_t)blockIdx.x * NE + cwbase;
#pragma unroll
        for (int jf = 0; jf < 16; ++jf) {
            float4 st;
            st.x = pcol[jf][0]; st.y = pcol[jf][1]; st.z = pcol[jf][2]; st.w = pcol[jf][3];
            *(float4*)(pp + jf * 16 + lg * 4) = st;
        }
    }
}

// Exact fp32 re-scan for flagged rows, 4 rows per codebook pass.
// Patches mrow, counts, and the z_q row.
__launch_bounds__(256)
__global__ void k_recheck(const float* __restrict__ z, const float* __restrict__ cb32,
                          const int* __restrict__ flagcnt, const int* __restrict__ flaglist,
                          float* __restrict__ mrow, float* __restrict__ counts,
                          float* __restrict__ zq) {
    __shared__ float zn[4][ED];
    __shared__ float rbv[4][4];
    __shared__ int   rbi[4][4];
    __shared__ int   rrow[4];
    __shared__ int   bsel[4];
    const int n = *flagcnt;
    const int tid = threadIdx.x, lane = tid & 63, wv = tid >> 6;
    for (int base = blockIdx.x * 4; base < n; base += gridDim.x * 4) {
        __syncthreads();
        {
            const int e = base + wv;
            int row = 0;
            if (e < n) row = flaglist[e];
            if (lane == 0) rrow[wv] = (e < n) ? row : -1;
            float v = (e < n) ? z[(size_t)row * ED + lane] : 0.f;
            float sq = v * v;
#pragma unroll
            for (int d = 32; d > 0; d >>= 1) sq += __shfl_xor(sq, d);
            zn[wv][lane] = v * (1.0f / fmaxf(sqrtf(sq), 1e-12f));
        }
        __syncthreads();
        float b0 = -2.f, b1 = -2.f, b2 = -2.f, b3 = -2.f;
        int i0 = 0, i1 = 0, i2 = 0, i3 = 0;
        for (int q = 0; q < 8; ++q) {
            const int j = q * 256 + tid;
            const float* cj = cb32 + (size_t)j * ED;
            float a0 = 0.f, a1 = 0.f, a2 = 0.f, a3 = 0.f;
#pragma unroll
            for (int k = 0; k < ED; k += 4) {
                const float4 c4 = *(const float4*)(cj + k);
                a0 = fmaf(zn[0][k], c4.x, a0); a0 = fmaf(zn[0][k+1], c4.y, a0);
                a0 = fmaf(zn[0][k+2], c4.z, a0); a0 = fmaf(zn[0][k+3], c4.w, a0);
                a1 = fmaf(zn[1][k], c4.x, a1); a1 = fmaf(zn[1][k+1], c4.y, a1);
                a1 = fmaf(zn[1][k+2], c4.z, a1); a1 = fmaf(zn[1][k+3], c4.w, a1);
                a2 = fmaf(zn[2][k], c4.x, a2); a2 = fmaf(zn[2][k+1], c4.y, a2);
                a2 = fmaf(zn[2][k+2], c4.z, a2); a2 = fmaf(zn[2][k+3], c4.w, a2);
                a3 = fmaf(zn[3][k], c4.x, a3); a3 = fmaf(zn[3][k+1], c4.y, a3);
                a3 = fmaf(zn[3][k+2], c4.z, a3); a3 = fmaf(zn[3][k+3], c4.w, a3);
            }
            i0 = (a0 > b0) ? j : i0; b0 = fmaxf(a0, b0);
            i1 = (a1 > b1) ? j : i1; b1 = fmaxf(a1, b1);
            i2 = (a2 > b2) ? j : i2; b2 = fmaxf(a2, b2);
            i3 = (a3 > b3) ? j : i3; b3 = fmaxf(a3, b3);
        }
#pragma unroll
        for (int d = 1; d < 64; d <<= 1) {
            float o; int oi; bool tk;
            o = __shfl_xor(b0, d); oi = __shfl_xor(i0, d);
            tk = (o > b0) || (o == b0 && oi < i0); b0 = tk ? o : b0; i0 = tk ? oi : i0;
            o = __shfl_xor(b1, d); oi = __shfl_xor(i1, d);
            tk = (o > b1) || (o == b1 && oi < i1); b1 = tk ? o : b1; i1 = tk ? oi : i1;
            o = __shfl_xor(b2, d); oi = __shfl_xor(i2, d);
            tk = (o > b2) || (o == b2 && oi < i2); b2 = tk ? o : b2; i2 = tk ? oi : i2;
            o = __shfl_xor(b3, d); oi = __shfl_xor(i3, d);
            tk = (o > b3) || (o == b3 && oi < i3); b3 = tk ? o : b3; i3 = tk ? oi : i3;
        }
        if (lane == 0) {
            rbv[wv][0] = b0; rbi[wv][0] = i0; rbv[wv][1] = b1; rbi[wv][1] = i1;
            rbv[wv][2] = b2; rbi[wv][2] = i2; rbv[wv][3] = b3; rbi[wv][3] = i3;
        }
        __syncthreads();
        if (tid < 4) {
            const int e = base + tid;
            if (e < n) {
                float bv = rbv[0][tid]; int bi_ = rbi[0][tid];
#pragma unroll
                for (int u = 1; u < 4; ++u) {
                    const float o = rbv[u][tid]; const int oi = rbi[u][tid];
                    const bool tk = (o > bv) || (o == bv && oi < bi_);
                    bv = tk ? o : bv; bi_ = tk ? oi : bi_;
                }
                const int row = rrow[tid];
                mrow[row] = bv;
                bsel[tid] = bi_;
                atomicAdd(&counts[bi_], 1.0f);
            }
        }
        __syncthreads();
        {   // rewrite z_q rows with exact selection
            const int r = tid >> 6;       // 0..3
            if (base + r < n) {
                const int row = rrow[r];
                zq[(size_t)row * ED + lane] = cb32[(size_t)bsel[r] * ED + lane];
            }
        }
    }
}

// Parallel reductions: blocks 0..7 sum ppart columns; blocks 8..71 sum mrow.
__global__ void k_red(const float* __restrict__ ppart, const float* __restrict__ mrow,
                      float* __restrict__ psum, float* __restrict__ mpart, int nblk) {
    const int tid = threadIdx.x;
    if (blockIdx.x < 8) {
        const int col = blockIdx.x * 256 + tid;
        float s = 0.f;
        for (int sl = 0; sl < nblk; ++sl) s += ppart[(size_t)sl * NE + col];
        psum[col] = s;
    } else {
        __shared__ float lds[4];
        const int b = blockIdx.x - 8;     // 0..63
        const int r0 = b * 1024;
        float s = 0.f;
        for (int r = r0 + tid; r < r0 + 1024; r += 256) s += mrow[r];
        const int lane = tid & 63, wv = tid >> 6;
#pragma unroll
        for (int d = 32; d > 0; d >>= 1) s += __shfl_xor(s, d);
        if (lane == 0) lds[wv] = s;
        __syncthreads();
        if (tid == 0) mpart[b] = lds[0] + lds[1] + lds[2] + lds[3];
    }
}

__device__ __forceinline__ float block_reduce_1024(float v, float* lds, int lane, int wid) {
#pragma unroll
    for (int off = 32; off > 0; off >>= 1) v += __shfl_xor(v, off);
    if (lane == 0) lds[wid] = v;
    __syncthreads();
    float r = 0.f;
    if (wid == 0) {
        r = (lane < 16) ? lds[lane] : 0.f;
#pragma unroll
        for (int off = 8; off > 0; off >>= 1) r += __shfl_xor(r, off);
    }
    __syncthreads();
    return r;
}

__global__ void k_final(const float* __restrict__ counts, const float* __restrict__ psum,
                        const float* __restrict__ mpart, float* __restrict__ out) {
    __shared__ float lds[16];
    const int tid = threadIdx.x;          // 1024
    const int lane = tid & 63, wid = tid >> 6;
    float sm = (tid < 64) ? mpart[tid] : 0.f;
    float kl = 0.f, lb = 0.f, H = 0.f;
    const float LOGNE = logf((float)NE);
    for (int j = tid; j < NE; j += 1024) {
        const float p = psum[j] * (1.0f / NROWS);
        const float em = counts[j] * (1.0f / NROWS);
        kl += p * (logf(p) + LOGNE);
        lb += em * p;
        H += em * logf(em + 1e-6f);
    }
    sm = block_reduce_1024(sm, lds, lane, wid);
    kl = block_reduce_1024(kl, lds, lane, wid);
    lb = block_reduce_1024(lb, lds, lane, wid);
    H  = block_reduce_1024(H,  lds, lane, wid);
    if (tid == 0) {
        out[OUT_COMMIT] = 1.25f * (1.0f - sm * (1.0f / NROWS));
        out[OUT_KL] = kl;
        out[OUT_LB] = lb;
        out[OUT_PERP] = expf(-H);
    }
}

extern "C" void kernel_launch(void* const* d_in, const int* in_sizes, int n_in,
                              void* d_out, int out_size, void* d_ws, size_t ws_size,
                              hipStream_t stream) {
    const float* z   = (const float*)d_in[0];
    const float* emb = (const float*)d_in[1];
    float* out = (float*)d_out;
    float* ws  = (float*)d_ws;

    _Float16* cbh  = (_Float16*)(ws + WS_CBH);
    float* mrowp   = ws + WS_MROW;
    int* flagcnt   = (int*)(ws + WS_FLAGCNT);
    int* flaglist  = (int*)(ws + WS_FLAGLIST);
    float* counts  = ws + WS_COUNTS;
    float* psum    = ws + WS_PSUM;
    float* mpart   = ws + WS_MPART;
    float* ppart   = ws + WS_PPART;
    float* cb32    = out + OUT_CB;

    // adapt grid to workspace capacity (ws_size fixed per session -> deterministic)
    const int nblk = ((ws_size / 4) >= (size_t)(WS_PPART + 512 * NE)) ? 512 : 256;
    const int tpb = (NROWS / 16) / nblk;   // tiles per block

    hipMemsetAsync(flagcnt, 0, sizeof(int), stream);
    hipMemsetAsync(counts, 0, NE * sizeof(float), stream);

    k_cb      <<<512, 256, 0, stream>>>(emb, cbh, cb32);
    k_main    <<<nblk, 512, 0, stream>>>(z, cbh, cb32, out + OUT_ZQ, mrowp, ppart,
                                         flagcnt, flaglist, counts, tpb);
    k_recheck <<<512, 256, 0, stream>>>(z, cb32, flagcnt, flaglist, mrowp, counts,
                                        out + OUT_ZQ);
    k_red     <<<72, 256, 0, stream>>>(ppart, mrowp, psum, mpart, nblk);
    k_final   <<<1, 1024, 0, stream>>>(counts, psum, mpart, out);
}

// Round 6
// 338.607 us; speedup vs baseline: 1.0634x; 1.0567x over previous
//
#include <hip/hip_runtime.h>
#include <math.h>

#define NROWS 65536
#define ED 64
#define NE 2048
#define TAU 1e-3f

typedef _Float16 f16x8 __attribute__((ext_vector_type(8)));
typedef float f32x4 __attribute__((ext_vector_type(4)));

// workspace layout (float offsets) — ppart LAST so its slice count can adapt
#define WS_CBH      0        // fp16[2048*64] = 65536 float slots
#define WS_MROW     65536    // float[65536]
#define WS_FLAGCNT  131072   // int[1] (+pad)
#define WS_FLAGLIST 131088   // int[65536]
#define WS_COUNTS   196624   // float[2048]
#define WS_PSUM     198672   // float[4*2048] partials
#define WS_MPART    206864   // float[64] (+pad)
#define WS_PPART    206976   // float[nblk*2048]

// output layout (float offsets): z_q_st, commit, kl, lb, cb, perplexity
#define OUT_ZQ     0
#define OUT_COMMIT 4194304
#define OUT_KL     4194305
#define OUT_LB     4194306
#define OUT_CB     4194307
#define OUT_PERP   4325379

__global__ void k_cb(const float* __restrict__ emb, _Float16* __restrict__ cbh,
                     float* __restrict__ cbo) {
    int t = blockIdx.x * blockDim.x + threadIdx.x;
    int row = t >> 6;
    int lane = t & 63;
    if (row >= NE) return;
    float v = emb[row * ED + lane];
    float sq = v * v;
#pragma unroll
    for (int off = 32; off > 0; off >>= 1) sq += __shfl_xor(sq, off);
    float c = v * (1.0f / fmaxf(sqrtf(sq), 1e-12f));
    cbo[row * ED + lane] = c;
    cbh[row * ED + lane] = (_Float16)c;
}

// Transposed fused GEMM, TWO-PASS (recompute d in pass 2 => no acc[] registers).
// C layout: col(lane&15) = z-row, row(lane>>4)*4+i = codeword.
// nblk blocks x 512 threads (8 waves); wave w owns codewords [w*256, w*256+256).
__launch_bounds__(512, 2)
__global__ void k_main(const float* __restrict__ z, const _Float16* __restrict__ cbh,
                       const float* __restrict__ cb32, float* __restrict__ zq,
                       float* __restrict__ mrow, float* __restrict__ ppart,
                       int* __restrict__ flagcnt, int* __restrict__ flaglist,
                       float* __restrict__ counts, int tpb) {
    __shared__ float st_m[8][16], st_s[8][16];
    __shared__ int   st_i[8][16], st_c[8][16];
    __shared__ float st_mm[16];
    __shared__ int   idxs[16];

    const int tid = threadIdx.x;
    const int lane = tid & 63;
    const int w = tid >> 6;               // 0..7
    const int l15 = lane & 15;            // z-row within tile
    const int lg = lane >> 4;             // 0..3
    const int cwbase = w * 256;

    f32x4 pcol[16];
#pragma unroll
    for (int jf = 0; jf < 16; ++jf) pcol[jf] = (f32x4){0.f, 0.f, 0.f, 0.f};

    const _Float16* cwp = cbh + (size_t)(cwbase + l15) * ED + lg * 8;

    for (int t = 0; t < tpb; ++t) {
        const int rowbase = (blockIdx.x * tpb + t) * 16;
        // ---- load z slice, normalize, build fp16 B fragments ----
        const float4* zp4 = (const float4*)(z + (size_t)(rowbase + l15) * ED + lg * 8);
        const float4 za0 = zp4[0], za1 = zp4[1];     // k = lg*8 .. +7
        const float4 zb0 = zp4[8], zb1 = zp4[9];     // k = 32+lg*8 .. +7
        float sq = za0.x*za0.x + za0.y*za0.y + za0.z*za0.z + za0.w*za0.w
                 + za1.x*za1.x + za1.y*za1.y + za1.z*za1.z + za1.w*za1.w
                 + zb0.x*zb0.x + zb0.y*zb0.y + zb0.z*zb0.z + zb0.w*zb0.w
                 + zb1.x*zb1.x + zb1.y*zb1.y + zb1.z*zb1.z + zb1.w*zb1.w;
        sq += __shfl_xor(sq, 16);
        sq += __shfl_xor(sq, 32);
        const float invn = 1.0f / fmaxf(sqrtf(sq), 1e-12f);
        f16x8 bh0, bh1;
        bh0[0]=(_Float16)(za0.x*invn); bh0[1]=(_Float16)(za0.y*invn);
        bh0[2]=(_Float16)(za0.z*invn); bh0[3]=(_Float16)(za0.w*invn);
        bh0[4]=(_Float16)(za1.x*invn); bh0[5]=(_Float16)(za1.y*invn);
        bh0[6]=(_Float16)(za1.z*invn); bh0[7]=(_Float16)(za1.w*invn);
        bh1[0]=(_Float16)(zb0.x*invn); bh1[1]=(_Float16)(zb0.y*invn);
        bh1[2]=(_Float16)(zb0.z*invn); bh1[3]=(_Float16)(zb0.w*invn);
        bh1[4]=(_Float16)(zb1.x*invn); bh1[5]=(_Float16)(zb1.y*invn);
        bh1[6]=(_Float16)(zb1.z*invn); bh1[7]=(_Float16)(zb1.w*invn);

        // ---- PASS 1: max / argmax / sum(exp); nothing stored ----
        float m = -2.f, s = 0.f;
        int mi = 0;
#pragma unroll
        for (int jf = 0; jf < 16; ++jf) {
            const _Float16* ap = cwp + (size_t)jf * 16 * ED;
            const f16x8 a0 = *(const f16x8*)(ap);
            const f16x8 a1 = *(const f16x8*)(ap + 32);
            f32x4 c = (f32x4){0.f, 0.f, 0.f, 0.f};
            c = __builtin_amdgcn_mfma_f32_16x16x32_f16(a0, bh0, c, 0, 0, 0);
            c = __builtin_amdgcn_mfma_f32_16x16x32_f16(a1, bh1, c, 0, 0, 0);
            const int cw0 = cwbase + jf * 16 + lg * 4;
#pragma unroll
            for (int i = 0; i < 4; ++i) {
                const float v = c[i];
                mi = (v > m) ? (cw0 + i) : mi;
                m  = fmaxf(v, m);
                s += __expf(v);
            }
        }
        // reduce stats over the 4 lg lanes sharing this z-row
#pragma unroll
        for (int d = 16; d <= 32; d <<= 1) {
            const float om = __shfl_xor(m, d);
            const int   oi = __shfl_xor(mi, d);
            const float os = __shfl_xor(s, d);
            s += os;
            const bool take = (om > m) || (om == m && oi < mi);
            mi = take ? oi : mi;
            m  = take ? om : m;
        }
        if (lane < 16) {
            st_m[w][lane] = m; st_s[w][lane] = s; st_i[w][lane] = mi;
        }
        __syncthreads();
        // all-lane denominator combine
        float ss = 0.f;
#pragma unroll
        for (int u = 0; u < 8; ++u) ss += st_s[u][l15];
        const float r = 1.0f / ss;
        if (w == 0 && lane < 16) {        // argmax/m combine
            float mm = st_m[0][lane];
            int ii = st_i[0][lane];
#pragma unroll
            for (int u = 1; u < 8; ++u) {
                const float om = st_m[u][lane];
                const int oi = st_i[u][lane];
                const bool take = (om > mm) || (om == mm && oi < ii);
                ii = take ? oi : ii;
                mm = take ? om : mm;
            }
            mrow[rowbase + lane] = mm;
            idxs[lane] = ii;
            st_mm[lane] = mm;
        }
        __syncthreads();
        // ---- z_q gather (overlaps pass 2 issue) ----
#pragma unroll
        for (int rr = 0; rr < 2; ++rr) {
            const int r16 = w + rr * 8;
            zq[(size_t)(rowbase + r16) * ED + lane] = cb32[(size_t)idxs[r16] * ED + lane];
        }
        // ---- PASS 2: recompute d, accumulate p, count near-max ----
        const float thr = st_mm[l15] - TAU;
        int cnt = 0;
#pragma unroll
        for (int jf = 0; jf < 16; ++jf) {
            const _Float16* ap = cwp + (size_t)jf * 16 * ED;
            const f16x8 a0 = *(const f16x8*)(ap);
            const f16x8 a1 = *(const f16x8*)(ap + 32);
            f32x4 c = (f32x4){0.f, 0.f, 0.f, 0.f};
            c = __builtin_amdgcn_mfma_f32_16x16x32_f16(a0, bh0, c, 0, 0, 0);
            c = __builtin_amdgcn_mfma_f32_16x16x32_f16(a1, bh1, c, 0, 0, 0);
#pragma unroll
            for (int i = 0; i < 4; ++i) {
                const float v = c[i];
                pcol[jf][i] = fmaf(__expf(v), r, pcol[jf][i]);
                cnt += (v >= thr) ? 1 : 0;
            }
        }
        cnt += __shfl_xor(cnt, 16);
        cnt += __shfl_xor(cnt, 32);
        if (lane < 16) st_c[w][lane] = cnt;
        __syncthreads();
        if (w == 0 && lane < 16) {        // ambiguity decision + counts
            int tot = 0;
#pragma unroll
            for (int u = 0; u < 8; ++u) tot += st_c[u][lane];
            if (tot >= 2) {               // >=2 values within TAU of max -> exact recheck
                int e = atomicAdd(flagcnt, 1);
                flaglist[e] = rowbase + lane;
            } else {
                atomicAdd(&counts[idxs[lane]], 1.0f);
            }
        }
        // no tail sync needed: next tile touches disjoint LDS arrays before the
        // next barrier, and w==0 itself orders its own reads/writes.
    }
    // ---- epilogue: reduce pcol over the 16 l15 lanes, store block partial ----
#pragma unroll
    for (int jf = 0; jf < 16; ++jf) {
#pragma unroll
        for (int i = 0; i < 4; ++i) {
            float v = pcol[jf][i];
            v += __shfl_xor(v, 1);
            v += __shfl_xor(v, 2);
            v += __shfl_xor(v, 4);
            v += __shfl_xor(v, 8);
            pcol[jf][i] = v;
        }
    }
    if (l15 == 0) {
        float* pp = ppart + (size_t)blockIdx.x * NE + cwbase;
#pragma unroll
        for (int jf = 0; jf < 16; ++jf) {
            float4 st;
            st.x = pcol[jf][0]; st.y = pcol[jf][1]; st.z = pcol[jf][2]; st.w = pcol[jf][3];
            *(float4*)(pp + jf * 16 + lg * 4) = st;
        }
    }
}

// Exact fp32 re-scan for flagged rows, 4 rows per codebook pass.
// Patches mrow, counts, and the z_q row.
__launch_bounds__(256)
__global__ void k_recheck(const float* __restrict__ z, const float* __restrict__ cb32,
                          const int* __restrict__ flagcnt, const int* __restrict__ flaglist,
                          float* __restrict__ mrow, float* __restrict__ counts,
                          float* __restrict__ zq) {
    __shared__ float zn[4][ED];
    __shared__ float rbv[4][4];
    __shared__ int   rbi[4][4];
    __shared__ int   rrow[4];
    __shared__ int   bsel[4];
    const int n = *flagcnt;
    const int tid = threadIdx.x, lane = tid & 63, wv = tid >> 6;
    for (int base = blockIdx.x * 4; base < n; base += gridDim.x * 4) {
        __syncthreads();
        {
            const int e = base + wv;
            int row = 0;
            if (e < n) row = flaglist[e];
            if (lane == 0) rrow[wv] = (e < n) ? row : -1;
            float v = (e < n) ? z[(size_t)row * ED + lane] : 0.f;
            float sq = v * v;
#pragma unroll
            for (int d = 32; d > 0; d >>= 1) sq += __shfl_xor(sq, d);
            zn[wv][lane] = v * (1.0f / fmaxf(sqrtf(sq), 1e-12f));
        }
        __syncthreads();
        float b0 = -2.f, b1 = -2.f, b2 = -2.f, b3 = -2.f;
        int i0 = 0, i1 = 0, i2 = 0, i3 = 0;
        for (int q = 0; q < 8; ++q) {
            const int j = q * 256 + tid;
            const float* cj = cb32 + (size_t)j * ED;
            float a0 = 0.f, a1 = 0.f, a2 = 0.f, a3 = 0.f;
#pragma unroll
            for (int k = 0; k < ED; k += 4) {
                const float4 c4 = *(const float4*)(cj + k);
                a0 = fmaf(zn[0][k], c4.x, a0); a0 = fmaf(zn[0][k+1], c4.y, a0);
                a0 = fmaf(zn[0][k+2], c4.z, a0); a0 = fmaf(zn[0][k+3], c4.w, a0);
                a1 = fmaf(zn[1][k], c4.x, a1); a1 = fmaf(zn[1][k+1], c4.y, a1);
                a1 = fmaf(zn[1][k+2], c4.z, a1); a1 = fmaf(zn[1][k+3], c4.w, a1);
                a2 = fmaf(zn[2][k], c4.x, a2); a2 = fmaf(zn[2][k+1], c4.y, a2);
                a2 = fmaf(zn[2][k+2], c4.z, a2); a2 = fmaf(zn[2][k+3], c4.w, a2);
                a3 = fmaf(zn[3][k], c4.x, a3); a3 = fmaf(zn[3][k+1], c4.y, a3);
                a3 = fmaf(zn[3][k+2], c4.z, a3); a3 = fmaf(zn[3][k+3], c4.w, a3);
            }
            i0 = (a0 > b0) ? j : i0; b0 = fmaxf(a0, b0);
            i1 = (a1 > b1) ? j : i1; b1 = fmaxf(a1, b1);
            i2 = (a2 > b2) ? j : i2; b2 = fmaxf(a2, b2);
            i3 = (a3 > b3) ? j : i3; b3 = fmaxf(a3, b3);
        }
#pragma unroll
        for (int d = 1; d < 64; d <<= 1) {
            float o; int oi; bool tk;
            o = __shfl_xor(b0, d); oi = __shfl_xor(i0, d);
            tk = (o > b0) || (o == b0 && oi < i0); b0 = tk ? o : b0; i0 = tk ? oi : i0;
            o = __shfl_xor(b1, d); oi = __shfl_xor(i1, d);
            tk = (o > b1) || (o == b1 && oi < i1); b1 = tk ? o : b1; i1 = tk ? oi : i1;
            o = __shfl_xor(b2, d); oi = __shfl_xor(i2, d);
            tk = (o > b2) || (o == b2 && oi < i2); b2 = tk ? o : b2; i2 = tk ? oi : i2;
            o = __shfl_xor(b3, d); oi = __shfl_xor(i3, d);
            tk = (o > b3) || (o == b3 && oi < i3); b3 = tk ? o : b3; i3 = tk ? oi : i3;
        }
        if (lane == 0) {
            rbv[wv][0] = b0; rbi[wv][0] = i0; rbv[wv][1] = b1; rbi[wv][1] = i1;
            rbv[wv][2] = b2; rbi[wv][2] = i2; rbv[wv][3] = b3; rbi[wv][3] = i3;
        }
        __syncthreads();
        if (tid < 4) {
            const int e = base + tid;
            if (e < n) {
                float bv = rbv[0][tid]; int bi_ = rbi[0][tid];
#pragma unroll
                for (int u = 1; u < 4; ++u) {
                    const float o = rbv[u][tid]; const int oi = rbi[u][tid];
                    const bool tk = (o > bv) || (o == bv && oi < bi_);
                    bv = tk ? o : bv; bi_ = tk ? oi : bi_;
                }
                const int row = rrow[tid];
                mrow[row] = bv;
                bsel[tid] = bi_;
                atomicAdd(&counts[bi_], 1.0f);
            }
        }
        __syncthreads();
        {   // rewrite z_q rows with exact selection
            const int r = tid >> 6;       // 0..3
            if (base + r < n) {
                const int row = rrow[r];
                zq[(size_t)row * ED + lane] = cb32[(size_t)bsel[r] * ED + lane];
            }
        }
    }
}

// Reductions: blocks 0..31 sum ppart columns (4-way slice split);
// blocks 32..95 sum mrow (1024 rows each).
__global__ void k_red(const float* __restrict__ ppart, const float* __restrict__ mrow,
                      float* __restrict__ psum4, float* __restrict__ mpart, int nblk) {
    const int tid = threadIdx.x;
    if (blockIdx.x < 32) {
        const int q = blockIdx.x >> 3;          // slice group 0..3
        const int col = (blockIdx.x & 7) * 256 + tid;
        const int s0 = q * (nblk / 4), s1 = s0 + nblk / 4;
        float s = 0.f;
        for (int sl = s0; sl < s1; ++sl) s += ppart[(size_t)sl * NE + col];
        psum4[q * NE + col] = s;
    } else {
        __shared__ float lds[4];
        const int b = blockIdx.x - 32;          // 0..63
        const int r0 = b * 1024;
        float s = 0.f;
        for (int r = r0 + tid; r < r0 + 1024; r += 256) s += mrow[r];
        const int lane = tid & 63, wv = tid >> 6;
#pragma unroll
        for (int d = 32; d > 0; d >>= 1) s += __shfl_xor(s, d);
        if (lane == 0) lds[wv] = s;
        __syncthreads();
        if (tid == 0) mpart[b] = lds[0] + lds[1] + lds[2] + lds[3];
    }
}

__device__ __forceinline__ float block_reduce_1024(float v, float* lds, int lane, int wid) {
#pragma unroll
    for (int off = 32; off > 0; off >>= 1) v += __shfl_xor(v, off);
    if (lane == 0) lds[wid] = v;
    __syncthreads();
    float r = 0.f;
    if (wid == 0) {
        r = (lane < 16) ? lds[lane] : 0.f;
#pragma unroll
        for (int off = 8; off > 0; off >>= 1) r += __shfl_xor(r, off);
    }
    __syncthreads();
    return r;
}

__global__ void k_final(const float* __restrict__ counts, const float* __restrict__ psum4,
                        const float* __restrict__ mpart, float* __restrict__ out) {
    __shared__ float lds[16];
    const int tid = threadIdx.x;          // 1024
    const int lane = tid & 63, wid = tid >> 6;
    float sm = (tid < 64) ? mpart[tid] : 0.f;
    float kl = 0.f, lb = 0.f, H = 0.f;
    const float LOGNE = logf((float)NE);
    for (int j = tid; j < NE; j += 1024) {
        const float ps = psum4[j] + psum4[NE + j] + psum4[2 * NE + j] + psum4[3 * NE + j];
        const float p = ps * (1.0f / NROWS);
        const float em = counts[j] * (1.0f / NROWS);
        kl += p * (logf(p) + LOGNE);
        lb += em * p;
        H += em * logf(em + 1e-6f);
    }
    sm = block_reduce_1024(sm, lds, lane, wid);
    kl = block_reduce_1024(kl, lds, lane, wid);
    lb = block_reduce_1024(lb, lds, lane, wid);
    H  = block_reduce_1024(H,  lds, lane, wid);
    if (tid == 0) {
        out[OUT_COMMIT] = 1.25f * (1.0f - sm * (1.0f / NROWS));
        out[OUT_KL] = kl;
        out[OUT_LB] = lb;
        out[OUT_PERP] = expf(-H);
    }
}

extern "C" void kernel_launch(void* const* d_in, const int* in_sizes, int n_in,
                              void* d_out, int out_size, void* d_ws, size_t ws_size,
                              hipStream_t stream) {
    const float* z   = (const float*)d_in[0];
    const float* emb = (const float*)d_in[1];
    float* out = (float*)d_out;
    float* ws  = (float*)d_ws;

    _Float16* cbh  = (_Float16*)(ws + WS_CBH);
    float* mrowp   = ws + WS_MROW;
    int* flagcnt   = (int*)(ws + WS_FLAGCNT);
    int* flaglist  = (int*)(ws + WS_FLAGLIST);
    float* counts  = ws + WS_COUNTS;
    float* psum4   = ws + WS_PSUM;
    float* mpart   = ws + WS_MPART;
    float* ppart   = ws + WS_PPART;
    float* cb32    = out + OUT_CB;

    // adapt grid to workspace capacity (ws_size fixed per session -> deterministic)
    const size_t wsf = ws_size / 4;
    int nblk = 256;
    if (wsf >= (size_t)(WS_PPART + 1024 * NE)) nblk = 1024;
    else if (wsf >= (size_t)(WS_PPART + 512 * NE)) nblk = 512;
    const int tpb = (NROWS / 16) / nblk;   // tiles per block

    hipMemsetAsync(flagcnt, 0, sizeof(int), stream);
    hipMemsetAsync(counts, 0, NE * sizeof(float), stream);

    k_cb      <<<512, 256, 0, stream>>>(emb, cbh, cb32);
    k_main    <<<nblk, 512, 0, stream>>>(z, cbh, cb32, out + OUT_ZQ, mrowp, ppart,
                                         flagcnt, flaglist, counts, tpb);
    k_recheck <<<512, 256, 0, stream>>>(z, cb32, flagcnt, flaglist, mrowp, counts,
                                        out + OUT_ZQ);
    k_red     <<<96, 256, 0, stream>>>(ppart, mrowp, psum4, mpart, nblk);
    k_final   <<<1, 1024, 0, stream>>>(counts, psum4, mpart, out);
}

// Round 7
// 235.432 us; speedup vs baseline: 1.5295x; 1.4382x over previous
//
#include <hip/hip_runtime.h>
#include <math.h>

#define NROWS 65536
#define ED 64
#define NE 2048
#define TAU 1e-3f

typedef _Float16 f16x8 __attribute__((ext_vector_type(8)));
typedef float f32x4 __attribute__((ext_vector_type(4)));

// ---- workspace layout (float offsets): total ~1.85MB, safe ----
#define WS_CBH      0        // fp16[2048*64] = 65536 float slots
#define WS_RINV     65536    // float[65536]
#define WS_MROW     131072   // float[65536]
#define WS_IDX      196608   // int[65536]
#define WS_FLAGCNT  262144   // int[1] (+pad)
#define WS_FLAGLIST 262160   // int[65536]
#define WS_COUNTS   327696   // float[2048]
#define WS_PSUM     329744   // float[2048]
#define WS_MPART    331792   // float[64] (+pad)
#define WS_PPART    331904   // float[64*2048]

// ---- output layout (float offsets): z_q_st, commit, kl, lb, cb, perplexity ----
#define OUT_ZQ     0
#define OUT_COMMIT 4194304
#define OUT_KL     4194305
#define OUT_LB     4194306
#define OUT_CB     4194307
#define OUT_PERP   4325379

// ---- scratch inside the zq output region (fully overwritten by k_zqg later) ----
#define ZS_ZNORM   0         // fp16[65536*64]  -> 2097152 float slots
#define ZS_PM      2097152   // float[16*65536] -> 1048576 slots
#define ZS_PAUX    3145728   // u16[16*65536]   -> 524288 slots
#define ZS_PSH     3670016   // fp16[16*65536]  -> 524288 slots (ends at 4194304 exactly)

__global__ void k_cb(const float* __restrict__ emb, _Float16* __restrict__ cbh,
                     float* __restrict__ cbo) {
    int t = blockIdx.x * blockDim.x + threadIdx.x;
    int row = t >> 6;
    int lane = t & 63;
    if (row >= NE) return;
    float v = emb[row * ED + lane];
    float sq = v * v;
#pragma unroll
    for (int off = 32; off > 0; off >>= 1) sq += __shfl_xor(sq, off);
    float c = v * (1.0f / fmaxf(sqrtf(sq), 1e-12f));
    cbo[row * ED + lane] = c;
    cbh[row * ED + lane] = (_Float16)c;
}

// Normalize z rows -> fp16 znorm. 4 lanes per row (16 cols each).
__global__ void k_prep(const float* __restrict__ z, _Float16* __restrict__ znorm) {
    const int tid = threadIdx.x;
    const int lane = tid & 63;
    const int w = tid >> 6;
    const int row = blockIdx.x * 64 + w * 16 + (lane >> 2);
    const int q = lane & 3;
    const float4* zp = (const float4*)(z + (size_t)row * ED + q * 16);
    const float4 a = zp[0], b = zp[1], c = zp[2], d = zp[3];
    float sq = a.x*a.x + a.y*a.y + a.z*a.z + a.w*a.w
             + b.x*b.x + b.y*b.y + b.z*b.z + b.w*b.w
             + c.x*c.x + c.y*c.y + c.z*c.z + c.w*c.w
             + d.x*d.x + d.y*d.y + d.z*d.z + d.w*d.w;
    sq += __shfl_xor(sq, 1);
    sq += __shfl_xor(sq, 2);
    const float r = 1.0f / fmaxf(sqrtf(sq), 1e-12f);
    f16x8 h0, h1;
    h0[0]=(_Float16)(a.x*r); h0[1]=(_Float16)(a.y*r); h0[2]=(_Float16)(a.z*r); h0[3]=(_Float16)(a.w*r);
    h0[4]=(_Float16)(b.x*r); h0[5]=(_Float16)(b.y*r); h0[6]=(_Float16)(b.z*r); h0[7]=(_Float16)(b.w*r);
    h1[0]=(_Float16)(c.x*r); h1[1]=(_Float16)(c.y*r); h1[2]=(_Float16)(c.z*r); h1[3]=(_Float16)(c.w*r);
    h1[4]=(_Float16)(d.x*r); h1[5]=(_Float16)(d.y*r); h1[6]=(_Float16)(d.z*r); h1[7]=(_Float16)(d.w*r);
    f16x8* dst = (f16x8*)(znorm + (size_t)row * ED + q * 16);
    dst[0] = h0; dst[1] = h1;
}

// Stats kernel: barrier-free. Wave owns 128 codewords (A-frags resident, 64 VGPR),
// streams 16 row-tiles of 16 rows. Per-(group,row) partials written to zq scratch.
// C layout: col(lane&15)=z-row, row(lane>>4)*4+i = codeword.
__launch_bounds__(512, 2)
__global__ void k_s1(const _Float16* __restrict__ znorm, const _Float16* __restrict__ cbh,
                     float* __restrict__ pm, unsigned short* __restrict__ paux,
                     _Float16* __restrict__ psh) {
    const int tid = threadIdx.x;
    const int lane = tid & 63;
    const int w = tid >> 6;
    const int l15 = lane & 15;
    const int lg = lane >> 4;
    const int gw = blockIdx.x * 8 + w;
    const int g = gw & 15;            // codeword group (128 cw)
    const int split = gw >> 4;        // 0..255 (256 rows each)
    const int cwbase = g * 128;

    f16x8 af[8][2];
#pragma unroll
    for (int jf = 0; jf < 8; ++jf) {
        const _Float16* ap = cbh + (size_t)(cwbase + jf * 16 + l15) * ED + lg * 8;
        af[jf][0] = *(const f16x8*)(ap);
        af[jf][1] = *(const f16x8*)(ap + 32);
    }

    for (int t = 0; t < 16; ++t) {
        const int rowbase = split * 256 + t * 16;
        const _Float16* bp = znorm + (size_t)(rowbase + l15) * ED + lg * 8;
        const f16x8 b0 = *(const f16x8*)(bp);
        const f16x8 b1 = *(const f16x8*)(bp + 32);
        float m = -2.f, m2 = -2.f, s = 0.f;
        int mi = 0;
#pragma unroll
        for (int jf = 0; jf < 8; ++jf) {
            f32x4 c = (f32x4){0.f, 0.f, 0.f, 0.f};
            c = __builtin_amdgcn_mfma_f32_16x16x32_f16(af[jf][0], b0, c, 0, 0, 0);
            c = __builtin_amdgcn_mfma_f32_16x16x32_f16(af[jf][1], b1, c, 0, 0, 0);
            const int cw0 = cwbase + jf * 16 + lg * 4;
#pragma unroll
            for (int i = 0; i < 4; ++i) {
                const float v = c[i];
                m2 = fmaxf(m2, fminf(v, m));
                mi = (v > m) ? (cw0 + i) : mi;
                m  = fmaxf(v, m);
                s += __expf(v);
            }
        }
#pragma unroll
        for (int d = 16; d <= 32; d <<= 1) {
            const float om  = __shfl_xor(m, d);
            const float om2 = __shfl_xor(m2, d);
            const int   oi  = __shfl_xor(mi, d);
            const float os  = __shfl_xor(s, d);
            s += os;
            const float nm2 = fmaxf(fmaxf(m2, om2), fminf(m, om));
            const bool take = (om > m) || (om == m && oi < mi);
            mi = take ? oi : mi;
            m  = take ? om : m;
            m2 = nm2;
        }
        if (lane < 16) {
            const int row = rowbase + lane;
            pm[(size_t)g * NROWS + row] = m;
            paux[(size_t)g * NROWS + row] =
                (unsigned short)(((m - m2 < TAU) ? 2048 : 0) | mi);
            psh[(size_t)g * NROWS + row] = (_Float16)s;
        }
    }
}

// Per-row combine of the 16 group partials.
__global__ void k_comb(const float* __restrict__ pm, const unsigned short* __restrict__ paux,
                       const _Float16* __restrict__ psh, float* __restrict__ rinv,
                       float* __restrict__ mrow, int* __restrict__ idxw,
                       int* __restrict__ flagcnt, int* __restrict__ flaglist,
                       float* __restrict__ counts) {
    const int row = blockIdx.x * 256 + threadIdx.x;
    float mg[16];
    unsigned short ax[16];
    float s = 0.f;
#pragma unroll
    for (int g = 0; g < 16; ++g) {
        mg[g] = pm[(size_t)g * NROWS + row];
        ax[g] = paux[(size_t)g * NROWS + row];
        s += (float)psh[(size_t)g * NROWS + row];
    }
    float bm = -2.f; int bi = 0;
#pragma unroll
    for (int g = 0; g < 16; ++g) {
        if (mg[g] > bm) { bm = mg[g]; bi = ax[g] & 2047; }
    }
    int near = 0; bool fl = false;
#pragma unroll
    for (int g = 0; g < 16; ++g) {
        const bool nr = (mg[g] >= bm - TAU);
        near += nr ? 1 : 0;
        fl = fl || (nr && (ax[g] & 2048));
    }
    rinv[row] = 1.0f / s;
    mrow[row] = bm;
    idxw[row] = bi;
    if (fl || near >= 2) {
        int e = atomicAdd(flagcnt, 1);
        flaglist[e] = row;
    } else {
        atomicAdd(&counts[bi], 1.0f);
    }
}

// p accumulation: A=znorm, B=cb (resident, 32 cw/wave). Lane owns one codeword
// column per jf -> p accumulates as per-lane scalar. Barrier-free.
__launch_bounds__(512, 3)
__global__ void k_s2(const _Float16* __restrict__ znorm, const _Float16* __restrict__ cbh,
                     const float* __restrict__ rinv, float* __restrict__ ppart) {
    const int tid = threadIdx.x;
    const int lane = tid & 63;
    const int w = tid >> 6;
    const int l15 = lane & 15;
    const int lg = lane >> 4;
    const int gw = blockIdx.x * 8 + w;
    const int cwg = gw & 63;          // 32-cw group
    const int split = gw >> 6;        // 0..63 (1024 rows each)

    f16x8 bf[2][2];
#pragma unroll
    for (int jf = 0; jf < 2; ++jf) {
        const _Float16* bp = cbh + (size_t)(cwg * 32 + jf * 16 + l15) * ED + lg * 8;
        bf[jf][0] = *(const f16x8*)(bp);
        bf[jf][1] = *(const f16x8*)(bp + 32);
    }
    float pc0 = 0.f, pc1 = 0.f;

    for (int t = 0; t < 64; ++t) {
        const int rowbase = split * 1024 + t * 16;
        const _Float16* ap = znorm + (size_t)(rowbase + l15) * ED + lg * 8;
        const f16x8 a0 = *(const f16x8*)(ap);
        const f16x8 a1 = *(const f16x8*)(ap + 32);
        const int r0 = rowbase + lg * 4;
        const float rv0 = rinv[r0], rv1 = rinv[r0 + 1];
        const float rv2 = rinv[r0 + 2], rv3 = rinv[r0 + 3];
        f32x4 c0 = (f32x4){0.f, 0.f, 0.f, 0.f};
        c0 = __builtin_amdgcn_mfma_f32_16x16x32_f16(a0, bf[0][0], c0, 0, 0, 0);
        c0 = __builtin_amdgcn_mfma_f32_16x16x32_f16(a1, bf[0][1], c0, 0, 0, 0);
        f32x4 c1 = (f32x4){0.f, 0.f, 0.f, 0.f};
        c1 = __builtin_amdgcn_mfma_f32_16x16x32_f16(a0, bf[1][0], c1, 0, 0, 0);
        c1 = __builtin_amdgcn_mfma_f32_16x16x32_f16(a1, bf[1][1], c1, 0, 0, 0);
        pc0 += __expf(c0[0]) * rv0 + __expf(c0[1]) * rv1
             + __expf(c0[2]) * rv2 + __expf(c0[3]) * rv3;
        pc1 += __expf(c1[0]) * rv0 + __expf(c1[1]) * rv1
             + __expf(c1[2]) * rv2 + __expf(c1[3]) * rv3;
    }
    pc0 += __shfl_xor(pc0, 16); pc0 += __shfl_xor(pc0, 32);
    pc1 += __shfl_xor(pc1, 16); pc1 += __shfl_xor(pc1, 32);
    if (lg == 0) {
        float* pp = ppart + (size_t)split * NE + cwg * 32;
        pp[l15] = pc0;
        pp[16 + l15] = pc1;
    }
}

// z_q gather (fully overwrites the zq scratch region). 16 threads per row.
__global__ void k_zqg(const float* __restrict__ cb32, const int* __restrict__ idxw,
                      float* __restrict__ zq) {
    const int r = blockIdx.x * 16 + (threadIdx.x >> 4);
    const int q = threadIdx.x & 15;
    const int j = idxw[r];
    ((float4*)(zq + (size_t)r * ED))[q] = ((const float4*)(cb32 + (size_t)j * ED))[q];
}

// Exact fp32 re-scan for flagged rows, 4 rows per codebook pass.
__launch_bounds__(256)
__global__ void k_recheck(const float* __restrict__ z, const float* __restrict__ cb32,
                          const int* __restrict__ flagcnt, const int* __restrict__ flaglist,
                          float* __restrict__ mrow, float* __restrict__ counts,
                          float* __restrict__ zq) {
    __shared__ float zn[4][ED];
    __shared__ float rbv[4][4];
    __shared__ int   rbi[4][4];
    __shared__ int   rrow[4];
    __shared__ int   bsel[4];
    const int n = *flagcnt;
    const int tid = threadIdx.x, lane = tid & 63, wv = tid >> 6;
    for (int base = blockIdx.x * 4; base < n; base += gridDim.x * 4) {
        __syncthreads();
        {
            const int e = base + wv;
            int row = 0;
            if (e < n) row = flaglist[e];
            if (lane == 0) rrow[wv] = (e < n) ? row : -1;
            float v = (e < n) ? z[(size_t)row * ED + lane] : 0.f;
            float sq = v * v;
#pragma unroll
            for (int d = 32; d > 0; d >>= 1) sq += __shfl_xor(sq, d);
            zn[wv][lane] = v * (1.0f / fmaxf(sqrtf(sq), 1e-12f));
        }
        __syncthreads();
        float b0 = -2.f, b1 = -2.f, b2 = -2.f, b3 = -2.f;
        int i0 = 0, i1 = 0, i2 = 0, i3 = 0;
        for (int q = 0; q < 8; ++q) {
            const int j = q * 256 + tid;
            const float* cj = cb32 + (size_t)j * ED;
            float a0 = 0.f, a1 = 0.f, a2 = 0.f, a3 = 0.f;
#pragma unroll
            for (int k = 0; k < ED; k += 4) {
                const float4 c4 = *(const float4*)(cj + k);
                a0 = fmaf(zn[0][k], c4.x, a0); a0 = fmaf(zn[0][k+1], c4.y, a0);
                a0 = fmaf(zn[0][k+2], c4.z, a0); a0 = fmaf(zn[0][k+3], c4.w, a0);
                a1 = fmaf(zn[1][k], c4.x, a1); a1 = fmaf(zn[1][k+1], c4.y, a1);
                a1 = fmaf(zn[1][k+2], c4.z, a1); a1 = fmaf(zn[1][k+3], c4.w, a1);
                a2 = fmaf(zn[2][k], c4.x, a2); a2 = fmaf(zn[2][k+1], c4.y, a2);
                a2 = fmaf(zn[2][k+2], c4.z, a2); a2 = fmaf(zn[2][k+3], c4.w, a2);
                a3 = fmaf(zn[3][k], c4.x, a3); a3 = fmaf(zn[3][k+1], c4.y, a3);
                a3 = fmaf(zn[3][k+2], c4.z, a3); a3 = fmaf(zn[3][k+3], c4.w, a3);
            }
            i0 = (a0 > b0) ? j : i0; b0 = fmaxf(a0, b0);
            i1 = (a1 > b1) ? j : i1; b1 = fmaxf(a1, b1);
            i2 = (a2 > b2) ? j : i2; b2 = fmaxf(a2, b2);
            i3 = (a3 > b3) ? j : i3; b3 = fmaxf(a3, b3);
        }
#pragma unroll
        for (int d = 1; d < 64; d <<= 1) {
            float o; int oi; bool tk;
            o = __shfl_xor(b0, d); oi = __shfl_xor(i0, d);
            tk = (o > b0) || (o == b0 && oi < i0); b0 = tk ? o : b0; i0 = tk ? oi : i0;
            o = __shfl_xor(b1, d); oi = __shfl_xor(i1, d);
            tk = (o > b1) || (o == b1 && oi < i1); b1 = tk ? o : b1; i1 = tk ? oi : i1;
            o = __shfl_xor(b2, d); oi = __shfl_xor(i2, d);
            tk = (o > b2) || (o == b2 && oi < i2); b2 = tk ? o : b2; i2 = tk ? oi : i2;
            o = __shfl_xor(b3, d); oi = __shfl_xor(i3, d);
            tk = (o > b3) || (o == b3 && oi < i3); b3 = tk ? o : b3; i3 = tk ? oi : i3;
        }
        if (lane == 0) {
            rbv[wv][0] = b0; rbi[wv][0] = i0; rbv[wv][1] = b1; rbi[wv][1] = i1;
            rbv[wv][2] = b2; rbi[wv][2] = i2; rbv[wv][3] = b3; rbi[wv][3] = i3;
        }
        __syncthreads();
        if (tid < 4) {
            const int e = base + tid;
            if (e < n) {
                float bv = rbv[0][tid]; int bi_ = rbi[0][tid];
#pragma unroll
                for (int u = 1; u < 4; ++u) {
                    const float o = rbv[u][tid]; const int oi = rbi[u][tid];
                    const bool tk = (o > bv) || (o == bv && oi < bi_);
                    bv = tk ? o : bv; bi_ = tk ? oi : bi_;
                }
                const int row = rrow[tid];
                mrow[row] = bv;
                bsel[tid] = bi_;
                atomicAdd(&counts[bi_], 1.0f);
            }
        }
        __syncthreads();
        {
            const int r = tid >> 6;
            if (base + r < n) {
                const int row = rrow[r];
                zq[(size_t)row * ED + lane] = cb32[(size_t)bsel[r] * ED + lane];
            }
        }
    }
}

// Reductions: blocks 0..7 sum ppart columns (64 slices); blocks 8..71 sum mrow.
__global__ void k_red(const float* __restrict__ ppart, const float* __restrict__ mrow,
                      float* __restrict__ psum, float* __restrict__ mpart) {
    const int tid = threadIdx.x;
    if (blockIdx.x < 8) {
        const int col = blockIdx.x * 256 + tid;
        float s = 0.f;
        for (int sl = 0; sl < 64; ++sl) s += ppart[(size_t)sl * NE + col];
        psum[col] = s;
    } else {
        __shared__ float lds[4];
        const int b = blockIdx.x - 8;     // 0..63
        const int r0 = b * 1024;
        float s = 0.f;
        for (int r = r0 + tid; r < r0 + 1024; r += 256) s += mrow[r];
        const int lane = tid & 63, wv = tid >> 6;
#pragma unroll
        for (int d = 32; d > 0; d >>= 1) s += __shfl_xor(s, d);
        if (lane == 0) lds[wv] = s;
        __syncthreads();
        if (tid == 0) mpart[b] = lds[0] + lds[1] + lds[2] + lds[3];
    }
}

__device__ __forceinline__ float block_reduce_1024(float v, float* lds, int lane, int wid) {
#pragma unroll
    for (int off = 32; off > 0; off >>= 1) v += __shfl_xor(v, off);
    if (lane == 0) lds[wid] = v;
    __syncthreads();
    float r = 0.f;
    if (wid == 0) {
        r = (lane < 16) ? lds[lane] : 0.f;
#pragma unroll
        for (int off = 8; off > 0; off >>= 1) r += __shfl_xor(r, off);
    }
    __syncthreads();
    return r;
}

__global__ void k_final(const float* __restrict__ counts, const float* __restrict__ psum,
                        const float* __restrict__ mpart, float* __restrict__ out) {
    __shared__ float lds[16];
    const int tid = threadIdx.x;          // 1024
    const int lane = tid & 63, wid = tid >> 6;
    float sm = (tid < 64) ? mpart[tid] : 0.f;
    float kl = 0.f, lb = 0.f, H = 0.f;
    const float LOGNE = logf((float)NE);
    for (int j = tid; j < NE; j += 1024) {
        const float p = psum[j] * (1.0f / NROWS);
        const float em = counts[j] * (1.0f / NROWS);
        kl += p * (logf(p) + LOGNE);
        lb += em * p;
        H += em * logf(em + 1e-6f);
    }
    sm = block_reduce_1024(sm, lds, lane, wid);
    kl = block_reduce_1024(kl, lds, lane, wid);
    lb = block_reduce_1024(lb, lds, lane, wid);
    H  = block_reduce_1024(H,  lds, lane, wid);
    if (tid == 0) {
        out[OUT_COMMIT] = 1.25f * (1.0f - sm * (1.0f / NROWS));
        out[OUT_KL] = kl;
        out[OUT_LB] = lb;
        out[OUT_PERP] = expf(-H);
    }
}

extern "C" void kernel_launch(void* const* d_in, const int* in_sizes, int n_in,
                              void* d_out, int out_size, void* d_ws, size_t ws_size,
                              hipStream_t stream) {
    const float* z   = (const float*)d_in[0];
    const float* emb = (const float*)d_in[1];
    float* out = (float*)d_out;
    float* ws  = (float*)d_ws;

    _Float16* cbh  = (_Float16*)(ws + WS_CBH);
    float* rinv    = ws + WS_RINV;
    float* mrowp   = ws + WS_MROW;
    int* idxw      = (int*)(ws + WS_IDX);
    int* flagcnt   = (int*)(ws + WS_FLAGCNT);
    int* flaglist  = (int*)(ws + WS_FLAGLIST);
    float* counts  = ws + WS_COUNTS;
    float* psum    = ws + WS_PSUM;
    float* mpart   = ws + WS_MPART;
    float* ppart   = ws + WS_PPART;
    float* cb32    = out + OUT_CB;
    float* zq      = out + OUT_ZQ;

    // scratch aliased into the zq output region (overwritten by k_zqg/k_recheck)
    _Float16* znorm      = (_Float16*)(zq + ZS_ZNORM);
    float* pm            = zq + ZS_PM;
    unsigned short* paux = (unsigned short*)(zq + ZS_PAUX);
    _Float16* psh        = (_Float16*)(zq + ZS_PSH);

    hipMemsetAsync(flagcnt, 0, sizeof(int), stream);
    hipMemsetAsync(counts, 0, NE * sizeof(float), stream);

    k_cb      <<<512, 256, 0, stream>>>(emb, cbh, cb32);
    k_prep    <<<1024, 256, 0, stream>>>(z, znorm);
    k_s1      <<<512, 512, 0, stream>>>(znorm, cbh, pm, paux, psh);
    k_comb    <<<256, 256, 0, stream>>>(pm, paux, psh, rinv, mrowp, idxw,
                                        flagcnt, flaglist, counts);
    k_s2      <<<512, 512, 0, stream>>>(znorm, cbh, rinv, ppart);
    k_zqg     <<<4096, 256, 0, stream>>>(cb32, idxw, zq);
    k_recheck <<<512, 256, 0, stream>>>(z, cb32, flagcnt, flaglist, mrowp, counts, zq);
    k_red     <<<72, 256, 0, stream>>>(ppart, mrowp, psum, mpart);
    k_final   <<<1, 1024, 0, stream>>>(counts, psum, mpart, out);
}